// Round 7
// baseline (124.445 us; speedup 1.0000x reference)
//
#include <hip/hip_runtime.h>
#include <hip/hip_bf16.h>
#include <math.h>

// Shapes
#define QL 32768
#define DD 1024
#define NTOK 64

using short8   = __attribute__((ext_vector_type(8))) short;
using f32x4    = __attribute__((ext_vector_type(4))) float;
using float4v  = __attribute__((ext_vector_type(4))) float;
using ushort4v = __attribute__((ext_vector_type(4))) unsigned short;
using ushort8v = __attribute__((ext_vector_type(8))) unsigned short;

// RNE f32->bf16 via bit trick (exact RNE)
__device__ __forceinline__ unsigned short f2bf(float f) {
    unsigned int u = __float_as_uint(f);
    unsigned int r = (u + 0x7FFFu + ((u >> 16) & 1u)) >> 16;
    return (unsigned short)r;
}

// async global->LDS, 16B per lane; dest = wave-uniform base + lane*16
__device__ __forceinline__ void gload_lds16(const void* g, void* l) {
    __builtin_amdgcn_global_load_lds(
        (const __attribute__((address_space(1))) void*)g,
        (__attribute__((address_space(3))) void*)l,
        16, 0, 0);
}

// ---------------------------------------------------------------------------
// Prologue 1: transpose-convert Wq -> WqT bf16, Pv -> PvT bf16.
// ---------------------------------------------------------------------------
__global__ __launch_bounds__(256) void prep_transpose_kernel(
        const float* __restrict__ Wq, const float* __restrict__ Pv,
        unsigned short* __restrict__ WqT, unsigned short* __restrict__ PvT) {
    __shared__ float tile[64][65];
    int b = blockIdx.x;
    const float* src; unsigned short* dst; int R, C, r0, c0;
    if (b < 256) { src = Wq; dst = WqT; R = 1024; C = 1024;
                   r0 = (b >> 4) << 6; c0 = (b & 15) << 6; }
    else         { b -= 256; src = Pv; dst = PvT; R = 64; C = 1024;
                   r0 = 0; c0 = b << 6; }
    const int tid = threadIdx.x;
#pragma unroll
    for (int i = 0; i < 16; ++i) {
        const int lin = tid + 256 * i;
        const int row = lin >> 6, col = lin & 63;
        if (r0 + row < R)
            tile[row][col] = src[(size_t)(r0 + row) * C + c0 + col];
    }
    __syncthreads();
#pragma unroll
    for (int i = 0; i < 16; ++i) {
        const int lin = tid + 256 * i;
        const int row = lin >> 6, col = lin & 63;
        if (r0 + col < R)
            dst[(size_t)(c0 + row) * R + r0 + col] = f2bf(tile[col][row]);
    }
}

// ---------------------------------------------------------------------------
// Prologue 2: Kp = Pk @ Wq via bf16 MFMA (B from WqT). grid 16 x 256.
// ---------------------------------------------------------------------------
__global__ __launch_bounds__(256) void kp_mfma_kernel(
        const float* __restrict__ Pk, const unsigned short* __restrict__ WqT,
        unsigned short* __restrict__ Kp) {
    const int tid = threadIdx.x;
    const int w   = tid >> 6;
    const int l   = tid & 63;
    const int lhi = l >> 4;
    const int llo = l & 15;
    const int N0  = blockIdx.x * 64;

    f32x4 acc[4];
#pragma unroll
    for (int ct = 0; ct < 4; ++ct) acc[ct] = (f32x4){0.f, 0.f, 0.f, 0.f};

    for (int kb = 0; kb < 32; ++kb) {
        const int k0 = kb * 32 + lhi * 8;
        float4v p0 = *(const float4v*)(Pk + (size_t)(w * 16 + llo) * DD + k0);
        float4v p1 = *(const float4v*)(Pk + (size_t)(w * 16 + llo) * DD + k0 + 4);
        short8 a;
        a[0] = (short)f2bf(p0.x); a[1] = (short)f2bf(p0.y);
        a[2] = (short)f2bf(p0.z); a[3] = (short)f2bf(p0.w);
        a[4] = (short)f2bf(p1.x); a[5] = (short)f2bf(p1.y);
        a[6] = (short)f2bf(p1.z); a[7] = (short)f2bf(p1.w);
#pragma unroll
        for (int ct = 0; ct < 4; ++ct) {
            short8 b = *(const short8*)(WqT + (size_t)(N0 + ct * 16 + llo) * DD + k0);
            acc[ct] = __builtin_amdgcn_mfma_f32_16x16x32_bf16(a, b, acc[ct], 0, 0, 0);
        }
    }
#pragma unroll
    for (int ct = 0; ct < 4; ++ct) {
#pragma unroll
        for (int j = 0; j < 4; ++j) {
            const int t = w * 16 + lhi * 4 + j;
            const int d = N0 + ct * 16 + llo;
            Kp[(size_t)t * DD + d] = f2bf(acc[ct][j]);
        }
    }
}

// ---------------------------------------------------------------------------
// Fused: s = x @ Kp^T -> row l2-norm*8 -> exact GELU -> y = s' @ Pv -> out.
// grid 2048 x 256 (4 waves). Block = 16 q-rows.
// Phase A: K = 4 tiles of 256 f32, global_load_lds dwordx4 double-buffered
//   (linear LDS dest, pre-swizzled global src chunk c <- c ^ (r&7); rule #21).
//   Wave w computes k-quarter [w*64, w*64+64) of every tile.
// Phase B: cross-wave reduce (sPart alias on staging LDS) + norm + GELU
//   -> s' bf16 [16][64] swizzled in LDS.
// Phase C: y = s' @ Pv swapped MFMA (D[m=d][n=q]), PvT frags from L2,
//   float4 stores. Wave w owns d-cols [w*256, w*256+256).
// ---------------------------------------------------------------------------
__global__ __launch_bounds__(256) void fused_kernel(
        const float* __restrict__ x, const unsigned short* __restrict__ Kp,
        const unsigned short* __restrict__ PvT, float* __restrict__ out) {
    __shared__ __align__(16) unsigned char smem[32768];
    unsigned char* sX0 = smem;              // staging buf 0 (16 KB)
    unsigned char* sX1 = smem + 16384;      // staging buf 1 (16 KB)
    unsigned char* sS  = smem + 20480;      // s' [16][128]B swizzled (2 KB, aliases sX1 tail)

    const int tid = threadIdx.x;
    const int w   = tid >> 6;
    const int l   = tid & 63;
    const int lhi = l >> 4;    // 0..3
    const int llo = l & 15;    // 0..15
    const int R0  = blockIdx.x * 16;
    const char* xbase = (const char*)x + (size_t)R0 * 4096;

    f32x4 acc[4];
#pragma unroll
    for (int ct = 0; ct < 4; ++ct) acc[ct] = (f32x4){0.f, 0.f, 0.f, 0.f};

    // stage tile t into buffer sb: instr j stages row r = w*4+j (1KB/wave-instr);
    // LDS chunk (r, lane) <- global chunk (r, lane ^ (r&7))
#define STAGE(t, sb)                                                            \
    {                                                                           \
        _Pragma("unroll")                                                       \
        for (int j = 0; j < 4; ++j) {                                           \
            const int r   = w * 4 + j;                                          \
            const int csw = l ^ (r & 7);                                        \
            gload_lds16(xbase + (size_t)r * 4096 + (t) * 1024 + csw * 16,       \
                        (void*)((sb) + r * 1024));                              \
        }                                                                       \
    }

#define COMPUTE(t, sb)                                                          \
    {                                                                           \
        _Pragma("unroll")                                                       \
        for (int ks = 0; ks < 2; ++ks) {                                        \
            const int c0 = w * 16 + ks * 8 + lhi * 2;                           \
            const int sw = llo & 7;                                             \
            const float4v f0 = *(const float4v*)((sb) + llo * 1024 + ((c0 ^ sw) << 4));       \
            const float4v f1 = *(const float4v*)((sb) + llo * 1024 + (((c0 + 1) ^ sw) << 4)); \
            short8 a;                                                           \
            ((__hip_bfloat162*)&a)[0] = __float22bfloat162_rn(float2{f0.x, f0.y}); \
            ((__hip_bfloat162*)&a)[1] = __float22bfloat162_rn(float2{f0.z, f0.w}); \
            ((__hip_bfloat162*)&a)[2] = __float22bfloat162_rn(float2{f1.x, f1.y}); \
            ((__hip_bfloat162*)&a)[3] = __float22bfloat162_rn(float2{f1.z, f1.w}); \
            const int kg = (t) * 256 + w * 64 + ks * 32 + lhi * 8;              \
            _Pragma("unroll")                                                   \
            for (int ct = 0; ct < 4; ++ct) {                                    \
                short8 bb = *(const short8*)(Kp + (size_t)(ct * 16 + llo) * DD + kg); \
                acc[ct] = __builtin_amdgcn_mfma_f32_16x16x32_bf16(a, bb, acc[ct], 0, 0, 0); \
            }                                                                   \
        }                                                                       \
    }

    STAGE(0, sX0);
    __syncthreads();
    STAGE(1, sX1);
    COMPUTE(0, sX0);
    __syncthreads();
    STAGE(2, sX0);
    COMPUTE(1, sX1);
    __syncthreads();
    STAGE(3, sX1);
    COMPUTE(2, sX0);
    __syncthreads();
    COMPUTE(3, sX1);
    __syncthreads();                 // staging LDS dead -> safe to alias
#undef STAGE
#undef COMPUTE

    // ---- Phase B: cross-wave reduce + row l2-norm*8 + exact GELU -> sS ----
    float (*sPart)[16][68] = (float (*)[16][68])(void*)smem;   // 17.4 KB alias
#pragma unroll
    for (int ct = 0; ct < 4; ++ct)
#pragma unroll
        for (int j = 0; j < 4; ++j)
            sPart[w][lhi * 4 + j][ct * 16 + llo] = acc[ct][j];
    __syncthreads();

    {
        const int r  = tid >> 4;          // 0..15
        const int cb = (tid & 15) * 4;    // token 4-group
        f32x4 v  = *(const f32x4*)&sPart[0][r][cb];
        f32x4 v1 = *(const f32x4*)&sPart[1][r][cb];
        f32x4 v2 = *(const f32x4*)&sPart[2][r][cb];
        f32x4 v3 = *(const f32x4*)&sPart[3][r][cb];
        v = v + v1 + v2 + v3;
        float ssq = v.x * v.x + v.y * v.y + v.z * v.z + v.w * v.w;
        ssq += __shfl_xor(ssq, 1);
        ssq += __shfl_xor(ssq, 2);
        ssq += __shfl_xor(ssq, 4);
        ssq += __shfl_xor(ssq, 8);
        const float scale = 8.0f / sqrtf(ssq);
        ushort4v g;
#pragma unroll
        for (int k = 0; k < 4; ++k) {
            const float vv = v[k] * scale;
            const float ge = 0.5f * vv * (1.0f + erff(vv * 0.70710678118654752f));
            g[k] = f2bf(ge);
        }
        *(ushort4v*)(sS + ((r * 128 + cb * 2) ^ ((r & 7) << 4))) = g;
    }
    __syncthreads();

    // ---- Phase C: y = s' @ Pv (swapped: D[m=d][n=q]); float4 stores ----
    short8 sb0 = *(const short8*)(sS + ((llo * 128 + lhi * 16)      ^ ((llo & 7) << 4)));
    short8 sb1 = *(const short8*)(sS + ((llo * 128 + 64 + lhi * 16) ^ ((llo & 7) << 4)));

    const int N0w = w * 256;
    float* orow = out + (size_t)(R0 + llo) * DD + N0w + lhi * 4;
#pragma unroll 4
    for (int dt = 0; dt < 16; ++dt) {
        const unsigned short* ap = PvT + (size_t)(N0w + dt * 16 + llo) * 64 + lhi * 8;
        short8 pa0 = *(const short8*)ap;
        short8 pa1 = *(const short8*)(ap + 32);
        f32x4 acc2 = (f32x4){0.f, 0.f, 0.f, 0.f};
        acc2 = __builtin_amdgcn_mfma_f32_16x16x32_bf16(pa0, sb0, acc2, 0, 0, 0);
        acc2 = __builtin_amdgcn_mfma_f32_16x16x32_bf16(pa1, sb1, acc2, 0, 0, 0);
        *(float4v*)(orow + dt * 16) = acc2;
    }
}

// ---------------------------------------------------------------------------
extern "C" void kernel_launch(void* const* d_in, const int* in_sizes, int n_in,
                              void* d_out, int out_size, void* d_ws, size_t ws_size,
                              hipStream_t stream) {
    (void)in_sizes; (void)n_in; (void)out_size; (void)ws_size;
    const float* x  = (const float*)d_in[0];
    const float* Wq = (const float*)d_in[1];
    const float* Pk = (const float*)d_in[2];
    const float* Pv = (const float*)d_in[3];
    float* out = (float*)d_out;

    // ws layout (2.25 MB total):
    //   WqT bf16 [1024][1024] @ 0            (2 MB)
    //   Kp  bf16 [64][1024]   @ 2 MB         (128 KB)
    //   PvT bf16 [1024][64]   @ 2 MB + 128K  (128 KB)
    unsigned short* WqT = (unsigned short*)d_ws;
    unsigned short* Kp  = (unsigned short*)((char*)d_ws + 2097152);
    unsigned short* PvT = (unsigned short*)((char*)d_ws + 2097152 + 131072);

    prep_transpose_kernel<<<272, 256, 0, stream>>>(Wq, Pv, WqT, PvT);
    kp_mfma_kernel<<<16, 256, 0, stream>>>(Pk, WqT, Kp);
    fused_kernel<<<2048, 256, 0, stream>>>(x, Kp, PvT, out);
}

// Round 8
// 100.019 us; speedup vs baseline: 1.2442x; 1.2442x over previous
//
#include <hip/hip_runtime.h>
#include <hip/hip_bf16.h>
#include <math.h>

// Shapes
#define QL 32768
#define DD 1024
#define NTOK 64

using short8   = __attribute__((ext_vector_type(8))) short;
using f32x4    = __attribute__((ext_vector_type(4))) float;
using float4v  = __attribute__((ext_vector_type(4))) float;
using ushort4v = __attribute__((ext_vector_type(4))) unsigned short;
using ushort8v = __attribute__((ext_vector_type(8))) unsigned short;

// RNE f32->bf16 via bit trick (exact RNE)
__device__ __forceinline__ unsigned short f2bf(float f) {
    unsigned int u = __float_as_uint(f);
    unsigned int r = (u + 0x7FFFu + ((u >> 16) & 1u)) >> 16;
    return (unsigned short)r;
}

// async global->LDS, 16B per lane; dest = wave-uniform base + lane*16
__device__ __forceinline__ void gload_lds16(const void* g, void* l) {
    __builtin_amdgcn_global_load_lds(
        (const __attribute__((address_space(1))) void*)g,
        (__attribute__((address_space(3))) void*)l,
        16, 0, 0);
}

// ---------------------------------------------------------------------------
// Prologue 1: transpose-convert Wq -> WqT bf16, Pv -> PvT bf16.
// ---------------------------------------------------------------------------
__global__ __launch_bounds__(256) void prep_transpose_kernel(
        const float* __restrict__ Wq, const float* __restrict__ Pv,
        unsigned short* __restrict__ WqT, unsigned short* __restrict__ PvT) {
    __shared__ float tile[64][65];
    int b = blockIdx.x;
    const float* src; unsigned short* dst; int R, C, r0, c0;
    if (b < 256) { src = Wq; dst = WqT; R = 1024; C = 1024;
                   r0 = (b >> 4) << 6; c0 = (b & 15) << 6; }
    else         { b -= 256; src = Pv; dst = PvT; R = 64; C = 1024;
                   r0 = 0; c0 = b << 6; }
    const int tid = threadIdx.x;
#pragma unroll
    for (int i = 0; i < 16; ++i) {
        const int lin = tid + 256 * i;
        const int row = lin >> 6, col = lin & 63;
        if (r0 + row < R)
            tile[row][col] = src[(size_t)(r0 + row) * C + c0 + col];
    }
    __syncthreads();
#pragma unroll
    for (int i = 0; i < 16; ++i) {
        const int lin = tid + 256 * i;
        const int row = lin >> 6, col = lin & 63;
        if (r0 + col < R)
            dst[(size_t)(c0 + row) * R + r0 + col] = f2bf(tile[col][row]);
    }
}

// ---------------------------------------------------------------------------
// Prologue 2: Kp = Pk @ Wq via bf16 MFMA (B from WqT). grid 16 x 256.
// ---------------------------------------------------------------------------
__global__ __launch_bounds__(256) void kp_mfma_kernel(
        const float* __restrict__ Pk, const unsigned short* __restrict__ WqT,
        unsigned short* __restrict__ Kp) {
    const int tid = threadIdx.x;
    const int w   = tid >> 6;
    const int l   = tid & 63;
    const int lhi = l >> 4;
    const int llo = l & 15;
    const int N0  = blockIdx.x * 64;

    f32x4 acc[4];
#pragma unroll
    for (int ct = 0; ct < 4; ++ct) acc[ct] = (f32x4){0.f, 0.f, 0.f, 0.f};

    for (int kb = 0; kb < 32; ++kb) {
        const int k0 = kb * 32 + lhi * 8;
        float4v p0 = *(const float4v*)(Pk + (size_t)(w * 16 + llo) * DD + k0);
        float4v p1 = *(const float4v*)(Pk + (size_t)(w * 16 + llo) * DD + k0 + 4);
        short8 a;
        a[0] = (short)f2bf(p0.x); a[1] = (short)f2bf(p0.y);
        a[2] = (short)f2bf(p0.z); a[3] = (short)f2bf(p0.w);
        a[4] = (short)f2bf(p1.x); a[5] = (short)f2bf(p1.y);
        a[6] = (short)f2bf(p1.z); a[7] = (short)f2bf(p1.w);
#pragma unroll
        for (int ct = 0; ct < 4; ++ct) {
            short8 b = *(const short8*)(WqT + (size_t)(N0 + ct * 16 + llo) * DD + k0);
            acc[ct] = __builtin_amdgcn_mfma_f32_16x16x32_bf16(a, b, acc[ct], 0, 0, 0);
        }
    }
#pragma unroll
    for (int ct = 0; ct < 4; ++ct) {
#pragma unroll
        for (int j = 0; j < 4; ++j) {
            const int t = w * 16 + lhi * 4 + j;
            const int d = N0 + ct * 16 + llo;
            Kp[(size_t)t * DD + d] = f2bf(acc[ct][j]);
        }
    }
}

// ---------------------------------------------------------------------------
// Fused: s = x @ Kp^T -> row l2-norm*8 -> exact GELU -> y = s' @ Pv.
// grid 1024 x 256 (4 waves). Block = 32 q-rows.
// Phase A: 16 K-steps of 64. 4-deep LDS circular buffer, global_load_lds
//   staging of BOTH A (x fp32, 8 KB/step) and B (Kp bf16, 8 KB/step).
//   Counted s_waitcnt vmcnt(8) + raw s_barrier per step — loads stay in
//   flight across barriers (T3/T4). Waves split tokens (wave w = tokens
//   w*16..w*16+16); A-frags broadcast from LDS.
//   Swizzle rule #21: linear LDS dest, inverse-swizzled global src,
//   swizzled read. A: 32B-granule XOR (row&7); B: 16B-chunk XOR (row&7).
// Phase B: s[32][64] f32 in LDS (alias buf A0/A1) -> row l2-norm*8 ->
//   exact GELU -> s' bf16 [32][128B] swizzled (alias buf B0).
// Phase C: y = s' @ Pv swapped MFMA (D[m=d][n=q]); PvT frags from L2;
//   float4 stores. Wave w owns d-cols [w*256, w*256+256).
// ---------------------------------------------------------------------------
__global__ __launch_bounds__(256) void fused_kernel(
        const float* __restrict__ x, const unsigned short* __restrict__ Kp,
        const unsigned short* __restrict__ PvT, float* __restrict__ out) {
    __shared__ __align__(16) unsigned char smem[65536];

    const int tid = threadIdx.x;
    const int w   = tid >> 6;
    const int l   = tid & 63;
    const int lhi = l >> 4;    // 0..3
    const int llo = l & 15;    // 0..15
    const int R0  = blockIdx.x * 32;
    const char* xb  = (const char*)x;
    const char* kpb = (const char*)Kp;

    f32x4 acc[2];
    acc[0] = (f32x4){0.f, 0.f, 0.f, 0.f};
    acc[1] = (f32x4){0.f, 0.f, 0.f, 0.f};

#define BUFA(b) (smem + (b) * 8192)
#define BUFB(b) (smem + 32768 + (b) * 8192)

    // stage K-step t into circular buffer t&3: per wave 2 A-instrs + 2 B-instrs.
    // A tile [32 rows][64 k f32] (256 B/row): instr i covers rows i*4..i*4+4,
    //   lane: row = i*4 + (l>>4), chunk16 = l&15, src chunk pre-XOR'ed ((row&7)<<1).
    // B tile [64 t][64 k bf16] (128 B/row): instr i covers rows i*8..i*8+8,
    //   lane: row = i*8 + (l>>3), chunk16 = l&7, src chunk pre-XOR'ed (row&7).
#define STAGE(t)                                                                \
    {                                                                           \
        const int bf_ = (t) & 3;                                                \
        _Pragma("unroll")                                                       \
        for (int j = 0; j < 2; ++j) {                                           \
            const int i  = w * 2 + j;                                           \
            const int ar = i * 4 + (l >> 4);                                    \
            const int ac = (l & 15) ^ ((ar & 7) << 1);                          \
            gload_lds16(xb + (size_t)(R0 + ar) * 4096 + (t) * 256 + ac * 16,    \
                        (void*)(BUFA(bf_) + i * 1024));                         \
            const int br = i * 8 + (l >> 3);                                    \
            const int bc = (l & 7) ^ (br & 7);                                  \
            gload_lds16(kpb + (size_t)br * 2048 + (t) * 128 + bc * 16,          \
                        (void*)(BUFB(bf_) + i * 1024));                         \
        }                                                                       \
    }

    // compute K-step t: wave w owns token-frag w*16..w*16+16 (ct = w),
    // 2 row-frags x 2 k-subs. A read: 32B granule (ks*4+lhi) ^ (row&7).
#define COMPUTE(t)                                                              \
    {                                                                           \
        const int bf_ = (t) & 3;                                                \
        _Pragma("unroll")                                                       \
        for (int ks = 0; ks < 2; ++ks) {                                        \
            const int brow = w * 16 + llo;                                      \
            const short8 b = *(const short8*)(BUFB(bf_) + brow * 128 +          \
                                  (((ks * 4 + lhi) ^ (brow & 7)) << 4));        \
            _Pragma("unroll")                                                   \
            for (int rf = 0; rf < 2; ++rf) {                                    \
                const int arow  = rf * 16 + llo;                                \
                const int abyte = arow * 256 +                                  \
                                  (((ks * 4 + lhi) ^ (arow & 7)) << 5);         \
                const float4v f0 = *(const float4v*)(BUFA(bf_) + abyte);        \
                const float4v f1 = *(const float4v*)(BUFA(bf_) + abyte + 16);   \
                short8 a;                                                       \
                ((__hip_bfloat162*)&a)[0] = __float22bfloat162_rn(float2{f0.x, f0.y}); \
                ((__hip_bfloat162*)&a)[1] = __float22bfloat162_rn(float2{f0.z, f0.w}); \
                ((__hip_bfloat162*)&a)[2] = __float22bfloat162_rn(float2{f1.x, f1.y}); \
                ((__hip_bfloat162*)&a)[3] = __float22bfloat162_rn(float2{f1.z, f1.w}); \
                acc[rf] = __builtin_amdgcn_mfma_f32_16x16x32_bf16(a, b, acc[rf], 0, 0, 0); \
            }                                                                   \
        }                                                                       \
    }

    // ---- Phase A: prologue stages 3 steps; loop keeps 2 steps in flight ----
    STAGE(0); STAGE(1); STAGE(2);
#pragma unroll
    for (int t = 0; t < 16; ++t) {
        if (t < 14)      { asm volatile("s_waitcnt vmcnt(8)" ::: "memory"); }
        else if (t == 14){ asm volatile("s_waitcnt vmcnt(4)" ::: "memory"); }
        else             { asm volatile("s_waitcnt vmcnt(0)" ::: "memory"); }
        __builtin_amdgcn_s_barrier();
        __builtin_amdgcn_sched_barrier(0);
        if (t < 13) { STAGE(t + 3); }   // overwrites buf (t-1)&3: safe after barrier
        COMPUTE(t);
    }
#undef STAGE
#undef COMPUTE

    // ---- Phase B: s partials -> LDS, row l2-norm*8 + exact GELU -> s' bf16 ----
    // sSf aliases buffers A0/A1 (compute(15) only touched buf 3 -> disjoint).
    float (*sSf)[68] = (float (*)[68])(void*)smem;         // [32][68] f32, 8.7 KB
#pragma unroll
    for (int rf = 0; rf < 2; ++rf)
#pragma unroll
        for (int j = 0; j < 4; ++j)
            sSf[rf * 16 + lhi * 4 + j][w * 16 + llo] = acc[rf][j];
    __syncthreads();

    unsigned char* sPb = smem + 32768;                     // s' [32][128]B swizzled (buf B0)
    {
        const int r = tid >> 3;           // 0..31 q-row
        const int g = tid & 7;            // token group of 8
        const f32x4 v0 = *(const f32x4*)&sSf[r][g * 8];
        const f32x4 v1 = *(const f32x4*)&sSf[r][g * 8 + 4];
        float ssq = v0.x * v0.x + v0.y * v0.y + v0.z * v0.z + v0.w * v0.w
                  + v1.x * v1.x + v1.y * v1.y + v1.z * v1.z + v1.w * v1.w;
        ssq += __shfl_xor(ssq, 1);
        ssq += __shfl_xor(ssq, 2);
        ssq += __shfl_xor(ssq, 4);
        const float scale = 8.0f / sqrtf(ssq);
        short8 gq;
#pragma unroll
        for (int k = 0; k < 4; ++k) {
            const float a0 = v0[k] * scale;
            const float a1 = v1[k] * scale;
            gq[k]     = (short)f2bf(0.5f * a0 * (1.0f + erff(a0 * 0.70710678118654752f)));
            gq[4 + k] = (short)f2bf(0.5f * a1 * (1.0f + erff(a1 * 0.70710678118654752f)));
        }
        *(short8*)(sPb + r * 128 + ((g ^ (r & 7)) << 4)) = gq;
    }
    __syncthreads();

    // ---- Phase C: y = s' @ Pv (swapped: D[m=d][n=q]); float4 stores ----
    short8 sb[2][2];
#pragma unroll
    for (int rh = 0; rh < 2; ++rh)
#pragma unroll
        for (int ks = 0; ks < 2; ++ks) {
            const int row = rh * 16 + llo;
            sb[rh][ks] = *(const short8*)(sPb + row * 128 +
                             (((ks * 4 + lhi) ^ (row & 7)) << 4));
        }

    const int N0w = w * 256;
#pragma unroll 2
    for (int dt = 0; dt < 16; ++dt) {
        const unsigned short* ap = PvT + (size_t)(N0w + dt * 16 + llo) * 64 + lhi * 8;
        const short8 pa0 = *(const short8*)ap;
        const short8 pa1 = *(const short8*)(ap + 32);
#pragma unroll
        for (int rh = 0; rh < 2; ++rh) {
            f32x4 c = (f32x4){0.f, 0.f, 0.f, 0.f};
            c = __builtin_amdgcn_mfma_f32_16x16x32_bf16(pa0, sb[rh][0], c, 0, 0, 0);
            c = __builtin_amdgcn_mfma_f32_16x16x32_bf16(pa1, sb[rh][1], c, 0, 0, 0);
            *(float4v*)(out + (size_t)(R0 + rh * 16 + llo) * DD + N0w + dt * 16 + lhi * 4) = c;
        }
    }
#undef BUFA
#undef BUFB
}

// ---------------------------------------------------------------------------
extern "C" void kernel_launch(void* const* d_in, const int* in_sizes, int n_in,
                              void* d_out, int out_size, void* d_ws, size_t ws_size,
                              hipStream_t stream) {
    (void)in_sizes; (void)n_in; (void)out_size; (void)ws_size;
    const float* x  = (const float*)d_in[0];
    const float* Wq = (const float*)d_in[1];
    const float* Pk = (const float*)d_in[2];
    const float* Pv = (const float*)d_in[3];
    float* out = (float*)d_out;

    // ws layout (2.25 MB total):
    //   WqT bf16 [1024][1024] @ 0            (2 MB)
    //   Kp  bf16 [64][1024]   @ 2 MB         (128 KB)
    //   PvT bf16 [1024][64]   @ 2 MB + 128K  (128 KB)
    unsigned short* WqT = (unsigned short*)d_ws;
    unsigned short* Kp  = (unsigned short*)((char*)d_ws + 2097152);
    unsigned short* PvT = (unsigned short*)((char*)d_ws + 2097152 + 131072);

    prep_transpose_kernel<<<272, 256, 0, stream>>>(Wq, Pv, WqT, PvT);
    kp_mfma_kernel<<<16, 256, 0, stream>>>(Pk, WqT, Kp);
    fused_kernel<<<1024, 256, 0, stream>>>(x, Kp, PvT, out);
}